// Round 1
// baseline (28.750 us; speedup 1.0000x reference)
//
#include <hip/hip_runtime.h>

// CrossNet: x_{l+1} = x0 * (xl . w_l) + xl + b_l, 3 layers, fused.
// BATCH=16384, DIM=1024, LAYER_NUM=3. One 64-lane wave per row:
// each lane holds 16 elements (4x float4), dot via 6-step shfl_xor reduce.
// Memory-bound: read x once (64 MiB) + write out once (64 MiB) ~= 20us floor.

#define CN_BATCH 16384
#define CN_DIM   1024
#define CN_LAYERS 3

__global__ __launch_bounds__(256) void crossnet_kernel(
    const float* __restrict__ x,
    const float* __restrict__ kernels,
    const float* __restrict__ bias,
    float* __restrict__ out)
{
    const int wave = threadIdx.x >> 6;          // 0..3 (4 rows per block)
    const int lane = threadIdx.x & 63;
    const int row  = (blockIdx.x << 2) + wave;  // grid sized exactly: no bounds check needed

    const float* xrow = x + (size_t)row * CN_DIM;

    // Lane l covers elements {j*256 + l*4 .. +3} for j=0..3 (coalesced float4 loads).
    float4 x0[4], xl[4];
#pragma unroll
    for (int j = 0; j < 4; ++j) {
        x0[j] = *reinterpret_cast<const float4*>(xrow + j * 256 + lane * 4);
        xl[j] = x0[j];
    }

#pragma unroll
    for (int i = 0; i < CN_LAYERS; ++i) {
        const float* krow = kernels + i * CN_DIM;
        const float* brow = bias    + i * CN_DIM;

        // Partial dot over this lane's 16 elements.
        float partial = 0.0f;
#pragma unroll
        for (int j = 0; j < 4; ++j) {
            float4 k = *reinterpret_cast<const float4*>(krow + j * 256 + lane * 4);
            partial = fmaf(xl[j].x, k.x, partial);
            partial = fmaf(xl[j].y, k.y, partial);
            partial = fmaf(xl[j].z, k.z, partial);
            partial = fmaf(xl[j].w, k.w, partial);
        }
        // 64-lane butterfly reduce -> s broadcast to all lanes.
#pragma unroll
        for (int off = 32; off >= 1; off >>= 1)
            partial += __shfl_xor(partial, off, 64);
        const float s = partial;

        // xl = x0 * s + xl + bias_i
#pragma unroll
        for (int j = 0; j < 4; ++j) {
            float4 b = *reinterpret_cast<const float4*>(brow + j * 256 + lane * 4);
            xl[j].x = fmaf(x0[j].x, s, xl[j].x) + b.x;
            xl[j].y = fmaf(x0[j].y, s, xl[j].y) + b.y;
            xl[j].z = fmaf(x0[j].z, s, xl[j].z) + b.z;
            xl[j].w = fmaf(x0[j].w, s, xl[j].w) + b.w;
        }
    }

    float* orow = out + (size_t)row * CN_DIM;
#pragma unroll
    for (int j = 0; j < 4; ++j)
        *reinterpret_cast<float4*>(orow + j * 256 + lane * 4) = xl[j];
}

extern "C" void kernel_launch(void* const* d_in, const int* in_sizes, int n_in,
                              void* d_out, int out_size, void* d_ws, size_t ws_size,
                              hipStream_t stream) {
    const float* x       = (const float*)d_in[0];
    const float* kernels = (const float*)d_in[1];
    const float* bias    = (const float*)d_in[2];
    float* out           = (float*)d_out;

    // 4 rows per 256-thread block.
    dim3 grid(CN_BATCH / 4);
    dim3 block(256);
    crossnet_kernel<<<grid, block, 0, stream>>>(x, kernels, bias, out);
}